// Round 20
// baseline (175.775 us; speedup 1.0000x reference)
//
#include <hip/hip_runtime.h>

#define DD 64
#define FIN 128
#define BK 256        // nodes per bucket
#define MAXBUK 512    // supports n <= 131072
#define CAP 8192      // records per bucket region (mean ~4092 at E=1.6M)
#define ESCAP 12288   // padded es slots per bucket
#define EPB 4096      // edges per block (16 per thread)

typedef _Float16 half8 __attribute__((ext_vector_type(8)));
typedef _Float16 h2 __attribute__((ext_vector_type(2)));
typedef float f32x4 __attribute__((ext_vector_type(4)));

union U4 { uint4 u; h2 h[4]; };

// build pass A: per-block bucket histogram -> hist2d[block][bucket] (coalesced)
__global__ __launch_bounds__(256) void k_histA(const int* __restrict__ dst,
                                               int* __restrict__ hist2d,
                                               int E, int nbuk) {
    __shared__ int hist[MAXBUK];
    int e0 = blockIdx.x * EPB;
    int e1 = min(e0 + EPB, E);
    for (int i = threadIdx.x; i < MAXBUK; i += 256) hist[i] = 0;
    __syncthreads();
    for (int e = e0 + threadIdx.x; e < e1; e += 256)
        atomicAdd(&hist[dst[e] >> 8], 1);
    __syncthreads();
    for (int i = threadIdx.x; i < MAXBUK; i += 256)
        hist2d[(size_t)blockIdx.x * MAXBUK + i] = hist[i];
}

// build pass B: column-wise exclusive scan of hist2d (thread j = bucket j),
// 8-row batched coalesced loads. gcur[j] = bucket total.
__global__ __launch_bounds__(512) void k_scan2(int* __restrict__ hist2d,
                                               int* __restrict__ gcur, int nb) {
    int j = threadIdx.x;
    int acc = 0;
    int r = 0;
    for (; r + 8 <= nb; r += 8) {
        int t[8];
#pragma unroll
        for (int i = 0; i < 8; ++i) t[i] = hist2d[(size_t)(r + i) * MAXBUK + j];
#pragma unroll
        for (int i = 0; i < 8; ++i) {
            hist2d[(size_t)(r + i) * MAXBUK + j] = acc;
            acc += t[i];
        }
    }
    for (; r < nb; ++r) {
        int t = hist2d[(size_t)r * MAXBUK + j];
        hist2d[(size_t)r * MAXBUK + j] = acc;
        acc += t;
    }
    gcur[j] = acc;
}

// build pass C: scatter edges into per-bucket regions using precomputed bases.
// NO global atomics.
__global__ __launch_bounds__(256) void k_bucket(const int* __restrict__ src,
                                                const int* __restrict__ dst,
                                                unsigned* __restrict__ buf,
                                                const int* __restrict__ hist2d,
                                                int E, int nbuk) {
    __shared__ int cur[MAXBUK];
    __shared__ int base[MAXBUK];
    int e0 = blockIdx.x * EPB;
    int e1 = min(e0 + EPB, E);
    for (int i = threadIdx.x; i < MAXBUK; i += 256) {
        cur[i] = 0;
        base[i] = hist2d[(size_t)blockIdx.x * MAXBUK + i];
    }
    __syncthreads();
#pragma unroll
    for (int i = 0; i < 16; ++i) {
        int e = e0 + threadIdx.x + i * 256;
        if (e < e1) {
            int d = dst[e];
            int b = d >> 8;
            int off = base[b] + atomicAdd(&cur[b], 1);
            if (off < CAP)
                buf[(size_t)b * CAP + off] = ((unsigned)src[e] << 8) | ((unsigned)d & 255u);
        }
    }
}

// pass 2: one workgroup per bucket. Per-node histogram -> padded (x16) scan ->
// es region at fixed b*ESCAP. Pads point at dummy row (index n, zeroed in gemm1).
__global__ __launch_bounds__(256) void k_csr(const unsigned* __restrict__ buf,
                                             const int* __restrict__ gcur,
                                             int* __restrict__ rowptr,
                                             int* __restrict__ lenp,
                                             float* __restrict__ rs,
                                             int* __restrict__ es, int n, int dummy) {
    __shared__ int cnt[BK];
    __shared__ int excl[BK];
    __shared__ int cur[BK];
    __shared__ int wsum[4];
    int b = blockIdx.x;
    int tid = threadIdx.x;
    int lane = tid & 63, wid = tid >> 6;
    cnt[tid] = 0;
    cur[tid] = 0;
    __syncthreads();
    int count = gcur[b];
    const unsigned* rec = buf + (size_t)b * CAP;
    for (int i = tid; i < count; i += 256)
        atomicAdd(&cnt[rec[i] & (BK - 1)], 1);
    __syncthreads();
    int v = cnt[tid];
    int pv = (v + 15) & ~15;  // padded to multiple of 16
    int s = pv;
    for (int off = 1; off < 64; off <<= 1) {
        int t = __shfl_up(s, off, 64);
        if (lane >= off) s += t;
    }
    if (lane == 63) wsum[wid] = s;
    __syncthreads();
    int wo = 0;
    for (int w = 0; w < wid; ++w) wo += wsum[w];
    excl[tid] = s - pv + wo;
    __syncthreads();
    int node = b * BK + tid;
    int base = b * ESCAP;
    if (node < n) {
        rowptr[node] = base + excl[tid];
        lenp[node] = pv;
        rs[node] = rsqrtf((float)(v + 1));  // +1 self-loop
    }
    for (int i = tid; i < count; i += 256) {
        unsigned r = rec[i];
        int local = r & (BK - 1);
        int pos = base + excl[local] + atomicAdd(&cur[local], 1);
        es[pos] = (int)(r >> 8);
    }
    int st = base + excl[tid];
    for (int i = v; i < pv; ++i) es[st + i] = dummy;
}

// transpose + f16-convert weights.
__global__ __launch_bounds__(256) void k_prep(const float* __restrict__ W1,
                                              const float* __restrict__ W2,
                                              _Float16* __restrict__ Wt1,
                                              _Float16* __restrict__ Wt2) {
    int tid = threadIdx.x;
    for (int i = tid; i < FIN * DD; i += 256) {
        int k = i >> 6, c = i & 63;
        Wt1[c * FIN + k] = (_Float16)W1[i];
    }
    for (int i = tid; i < DD * DD; i += 256) {
        int k = i >> 6, c = i & 63;
        Wt2[c * DD + k] = (_Float16)W2[i];
    }
}

// MFMA f16 GEMM: hpf[row][col] = f16((x[row,:] @ W[:,col]) * rs[row])
__global__ __launch_bounds__(256) void k_gemm1(const float* __restrict__ x,
                                               const _Float16* __restrict__ Wt,
                                               const float* __restrict__ rs,
                                               _Float16* __restrict__ hpf, int n) {
    __shared__ _Float16 sx[64 * 136];
    int row0 = blockIdx.x * 64;
    int tid = threadIdx.x;
    for (int i = tid; i < 2048; i += 256) {  // 64 rows * 32 float4
        int r = i >> 5, c = i & 31;
        int row = row0 + r;
        float4 v = make_float4(0.f, 0.f, 0.f, 0.f);
        if (row < n) v = *(const float4*)(x + (size_t)row * FIN + c * 4);
        union { _Float16 h[4]; uint2 u; } t;
        t.h[0] = (_Float16)v.x; t.h[1] = (_Float16)v.y;
        t.h[2] = (_Float16)v.z; t.h[3] = (_Float16)v.w;
        *(uint2*)(sx + r * 136 + c * 4) = t.u;
    }
    __syncthreads();
    int lane = tid & 63, wave = tid >> 6;
    int r15 = lane & 15, g = lane >> 4;
    half8 a[4];
    const _Float16* ap = sx + (wave * 16 + r15) * 136 + g * 8;
#pragma unroll
    for (int kc = 0; kc < 4; ++kc) a[kc] = *(const half8*)(ap + kc * 32);
    half8 bfr[4][4];
    const _Float16* bp = Wt + (size_t)r15 * FIN + g * 8;
#pragma unroll
    for (int ct = 0; ct < 4; ++ct)
#pragma unroll
        for (int kc = 0; kc < 4; ++kc)
            bfr[ct][kc] = *(const half8*)(bp + ct * 16 * FIN + kc * 32);
    f32x4 acc[4] = {{0.f,0.f,0.f,0.f},{0.f,0.f,0.f,0.f},{0.f,0.f,0.f,0.f},{0.f,0.f,0.f,0.f}};
#pragma unroll
    for (int ct = 0; ct < 4; ++ct)
#pragma unroll
        for (int kc = 0; kc < 4; ++kc)
            acc[ct] = __builtin_amdgcn_mfma_f32_16x16x32_f16(a[kc], bfr[ct][kc], acc[ct], 0, 0, 0);
    __syncthreads();
#pragma unroll
    for (int reg = 0; reg < 4; ++reg) {
        int rowl = wave * 16 + g * 4 + reg;
        int row = row0 + rowl;
        float sc = (row < n) ? rs[row] : 0.f;
#pragma unroll
        for (int ct = 0; ct < 4; ++ct)
            sx[rowl * 72 + ct * 16 + r15] = (_Float16)(acc[ct][reg] * sc);
    }
    __syncthreads();
    for (int i = tid; i < 1024; i += 256) {  // 64 rows * 16 uint2
        int r = i >> 4, q = i & 15;
        uint2 v = *(const uint2*)(sx + r * 72 + q * 4);
        *(uint2*)(hpf + (size_t)(row0 + r) * DD + q * 4) = v;
    }
}

// gather core: 16 nodes/wave, 4 lanes/node; lane owns chunks q and q+4 (32B).
#define GATHER_BODY                                                              \
    int e0 = rowptr[nc];                                                         \
    int len = alive ? lenp[nc] : 0;                                              \
    int nbt = len >> 4;                                                          \
    h2 ac[2][2][4] = {};                                                         \
    {                                                                            \
        U4 t0, t1;                                                               \
        t0.u = hp4[(size_t)nc * 8 + q];                                          \
        t1.u = hp4[(size_t)nc * 8 + q + 4];                                      \
        _Pragma("unroll")                                                        \
        for (int k = 0; k < 4; ++k) { ac[0][0][k] += t0.h[k]; ac[1][0][k] += t1.h[k]; } \
    }                                                                            \
    for (int t = 0; t < nbt; ++t) {                                              \
        uint4 eb = *(const uint4*)(es + e0 + t * 16 + q * 4);                    \
        int jj[16];                                                              \
        _Pragma("unroll")                                                        \
        for (int l = 0; l < 4; ++l) {                                            \
            jj[l]      = __shfl((int)eb.x, l, 4);                                \
            jj[4 + l]  = __shfl((int)eb.y, l, 4);                                \
            jj[8 + l]  = __shfl((int)eb.z, l, 4);                                \
            jj[12 + l] = __shfl((int)eb.w, l, 4);                                \
        }                                                                        \
        _Pragma("unroll")                                                        \
        for (int hb = 0; hb < 2; ++hb) {                                         \
            U4 v0[8], v1[8];                                                     \
            _Pragma("unroll")                                                    \
            for (int m = 0; m < 8; ++m) {                                        \
                size_t bb = (size_t)jj[hb * 8 + m] * 8;                          \
                v0[m].u = hp4[bb + q];                                           \
                v1[m].u = hp4[bb + q + 4];                                       \
            }                                                                    \
            _Pragma("unroll")                                                    \
            for (int m = 0; m < 8; ++m) {                                        \
                _Pragma("unroll")                                                \
                for (int k = 0; k < 4; ++k) {                                    \
                    ac[0][m & 1][k] += v0[m].h[k];                               \
                    ac[1][m & 1][k] += v1[m].h[k];                               \
                }                                                                \
            }                                                                    \
        }                                                                        \
    }                                                                            \
    float F0[8], F1[8];                                                          \
    _Pragma("unroll")                                                            \
    for (int k = 0; k < 4; ++k) {                                                \
        F0[2 * k]     = (float)ac[0][0][k].x + (float)ac[0][1][k].x;             \
        F0[2 * k + 1] = (float)ac[0][0][k].y + (float)ac[0][1][k].y;             \
        F1[2 * k]     = (float)ac[1][0][k].x + (float)ac[1][1][k].x;             \
        F1[2 * k + 1] = (float)ac[1][0][k].y + (float)ac[1][1][k].y;             \
    }

// fused agg1 + relu + gemm2: block = 64 consecutive nodes.
__global__ __launch_bounds__(256) void k_aggemm(const uint4* __restrict__ hp4,
                                                const int* __restrict__ es,
                                                const int* __restrict__ rowptr,
                                                const int* __restrict__ lenp,
                                                const float* __restrict__ rs,
                                                const float* __restrict__ b,
                                                const float* __restrict__ pert,
                                                const _Float16* __restrict__ Wt,
                                                _Float16* __restrict__ hpo, int n) {
    __shared__ _Float16 sx[64 * 72];
    int tid = threadIdx.x;
    int lane = tid & 63, wv = tid >> 6;
    int q = lane & 3, g = lane >> 2;
    int row0 = blockIdx.x * 64;
    int rowl = wv * 16 + g;
    int node = row0 + rowl;
    bool alive = node < n;
    int nc = alive ? node : 0;
    GATHER_BODY
    {
        float r = rs[nc];
        size_t op = (size_t)nc * DD + q * 8;
        float4 p0 = *(const float4*)(pert + op);
        float4 p1 = *(const float4*)(pert + op + 4);
        float4 p2 = *(const float4*)(pert + op + 32);
        float4 p3 = *(const float4*)(pert + op + 36);
        float4 b0 = *(const float4*)(b + q * 8);
        float4 b1 = *(const float4*)(b + q * 8 + 4);
        float4 b2 = *(const float4*)(b + q * 8 + 32);
        float4 b3 = *(const float4*)(b + q * 8 + 36);
        union { _Float16 h[8]; uint4 u; } t0, t1;
        float m = alive ? 1.f : 0.f;
        t0.h[0] = (_Float16)(m * fmaxf(fmaf(r, F0[0], b0.x + p0.x), 0.f));
        t0.h[1] = (_Float16)(m * fmaxf(fmaf(r, F0[1], b0.y + p0.y), 0.f));
        t0.h[2] = (_Float16)(m * fmaxf(fmaf(r, F0[2], b0.z + p0.z), 0.f));
        t0.h[3] = (_Float16)(m * fmaxf(fmaf(r, F0[3], b0.w + p0.w), 0.f));
        t0.h[4] = (_Float16)(m * fmaxf(fmaf(r, F0[4], b1.x + p1.x), 0.f));
        t0.h[5] = (_Float16)(m * fmaxf(fmaf(r, F0[5], b1.y + p1.y), 0.f));
        t0.h[6] = (_Float16)(m * fmaxf(fmaf(r, F0[6], b1.z + p1.z), 0.f));
        t0.h[7] = (_Float16)(m * fmaxf(fmaf(r, F0[7], b1.w + p1.w), 0.f));
        t1.h[0] = (_Float16)(m * fmaxf(fmaf(r, F1[0], b2.x + p2.x), 0.f));
        t1.h[1] = (_Float16)(m * fmaxf(fmaf(r, F1[1], b2.y + p2.y), 0.f));
        t1.h[2] = (_Float16)(m * fmaxf(fmaf(r, F1[2], b2.z + p2.z), 0.f));
        t1.h[3] = (_Float16)(m * fmaxf(fmaf(r, F1[3], b2.w + p2.w), 0.f));
        t1.h[4] = (_Float16)(m * fmaxf(fmaf(r, F1[4], b3.x + p3.x), 0.f));
        t1.h[5] = (_Float16)(m * fmaxf(fmaf(r, F1[5], b3.y + p3.y), 0.f));
        t1.h[6] = (_Float16)(m * fmaxf(fmaf(r, F1[6], b3.z + p3.z), 0.f));
        t1.h[7] = (_Float16)(m * fmaxf(fmaf(r, F1[7], b3.w + p3.w), 0.f));
        *(uint4*)(sx + rowl * 72 + q * 8) = t0.u;
        *(uint4*)(sx + rowl * 72 + q * 8 + 32) = t1.u;
    }
    __syncthreads();
    int r15 = lane & 15, gg = lane >> 4;
    half8 a[2];
    const _Float16* ap = sx + (wv * 16 + r15) * 72 + gg * 8;
#pragma unroll
    for (int kc = 0; kc < 2; ++kc) a[kc] = *(const half8*)(ap + kc * 32);
    half8 bfr[4][2];
    const _Float16* bp = Wt + (size_t)r15 * DD + gg * 8;
#pragma unroll
    for (int ct = 0; ct < 4; ++ct)
#pragma unroll
        for (int kc = 0; kc < 2; ++kc)
            bfr[ct][kc] = *(const half8*)(bp + ct * 16 * DD + kc * 32);
    f32x4 acc[4] = {{0.f,0.f,0.f,0.f},{0.f,0.f,0.f,0.f},{0.f,0.f,0.f,0.f},{0.f,0.f,0.f,0.f}};
#pragma unroll
    for (int ct = 0; ct < 4; ++ct)
#pragma unroll
        for (int kc = 0; kc < 2; ++kc)
            acc[ct] = __builtin_amdgcn_mfma_f32_16x16x32_f16(a[kc], bfr[ct][kc], acc[ct], 0, 0, 0);
    __syncthreads();
#pragma unroll
    for (int reg = 0; reg < 4; ++reg) {
        int rl = wv * 16 + gg * 4 + reg;
        int row = row0 + rl;
        float sc = (row < n) ? rs[row] : 0.f;
#pragma unroll
        for (int ct = 0; ct < 4; ++ct)
            sx[rl * 72 + ct * 16 + r15] = (_Float16)(acc[ct][reg] * sc);
    }
    __syncthreads();
    for (int i = tid; i < 1024; i += 256) {
        int r = i >> 4, qq = i & 15;
        uint2 v = *(const uint2*)(sx + r * 72 + qq * 4);
        *(uint2*)(hpo + (size_t)(row0 + r) * DD + qq * 4) = v;
    }
}

// final aggregation: gather layer-2 rows, epilogue, write f32 out.
__global__ __launch_bounds__(256) void k_agg2(const uint4* __restrict__ hp4,
                                              const int* __restrict__ es,
                                              const int* __restrict__ rowptr,
                                              const int* __restrict__ lenp,
                                              const float* __restrict__ rs,
                                              const float* __restrict__ b,
                                              const float* __restrict__ pert,
                                              float* __restrict__ outp, int n) {
    int tid = threadIdx.x;
    int lane = tid & 63, wv = tid >> 6;
    int q = lane & 3, g = lane >> 2;
    int node = blockIdx.x * 64 + wv * 16 + g;
    bool alive = node < n;
    int nc = alive ? node : 0;
    GATHER_BODY
    if (alive) {
        float r = rs[nc];
        size_t op = (size_t)nc * DD + q * 8;
        float4 p0 = *(const float4*)(pert + op);
        float4 p1 = *(const float4*)(pert + op + 4);
        float4 p2 = *(const float4*)(pert + op + 32);
        float4 p3 = *(const float4*)(pert + op + 36);
        float4 b0 = *(const float4*)(b + q * 8);
        float4 b1 = *(const float4*)(b + q * 8 + 4);
        float4 b2 = *(const float4*)(b + q * 8 + 32);
        float4 b3 = *(const float4*)(b + q * 8 + 36);
        float4 r0, r1, r2, r3;
        r0.x = fmaf(r, F0[0], b0.x + p0.x);
        r0.y = fmaf(r, F0[1], b0.y + p0.y);
        r0.z = fmaf(r, F0[2], b0.z + p0.z);
        r0.w = fmaf(r, F0[3], b0.w + p0.w);
        r1.x = fmaf(r, F0[4], b1.x + p1.x);
        r1.y = fmaf(r, F0[5], b1.y + p1.y);
        r1.z = fmaf(r, F0[6], b1.z + p1.z);
        r1.w = fmaf(r, F0[7], b1.w + p1.w);
        r2.x = fmaf(r, F1[0], b2.x + p2.x);
        r2.y = fmaf(r, F1[1], b2.y + p2.y);
        r2.z = fmaf(r, F1[2], b2.z + p2.z);
        r2.w = fmaf(r, F1[3], b2.w + p2.w);
        r3.x = fmaf(r, F1[4], b3.x + p3.x);
        r3.y = fmaf(r, F1[5], b3.y + p3.y);
        r3.z = fmaf(r, F1[6], b3.z + p3.z);
        r3.w = fmaf(r, F1[7], b3.w + p3.w);
        *(float4*)(outp + op) = r0;
        *(float4*)(outp + op + 4) = r1;
        *(float4*)(outp + op + 32) = r2;
        *(float4*)(outp + op + 36) = r3;
    }
}

extern "C" void kernel_launch(void* const* d_in, const int* in_sizes, int n_in,
                              void* d_out, int out_size, void* d_ws, size_t ws_size,
                              hipStream_t stream) {
    const float* x  = (const float*)d_in[0];
    const int*   ei = (const int*)d_in[1];
    const float* W1 = (const float*)d_in[2];
    const float* b1 = (const float*)d_in[3];
    const float* W2 = (const float*)d_in[4];
    const float* b2 = (const float*)d_in[5];
    const float* p1 = (const float*)d_in[6];
    const float* p2 = (const float*)d_in[7];
    float* out = (float*)d_out;

    int n = in_sizes[0] / FIN;
    int E = in_sizes[1] / 2;
    const int* src = ei;
    const int* dst = ei + E;
    int nbuk = (n + BK - 1) / BK;      // 391 for n=100k
    int nbb = (E + EPB - 1) / EPB;     // 391 edge blocks
    int gb = (n + 64) / 64;            // covers dummy row n

    char* ws = (char*)d_ws;
    size_t off = 0;
    int* gcur   = (int*)(ws + off); off += sizeof(int) * MAXBUK;
    int* rowptr = (int*)(ws + off); off += sizeof(int) * (size_t)n;
    int* lenp   = (int*)(ws + off); off += sizeof(int) * (size_t)n;
    float* rs   = (float*)(ws + off); off += sizeof(float) * (size_t)n;
    int* hist2d = (int*)(ws + off); off += sizeof(int) * (size_t)nbb * MAXBUK;
    int* es     = (int*)(ws + off); off += sizeof(int) * (size_t)nbuk * ESCAP;
    off = (off + 15) & ~(size_t)15;
    unsigned* buf = (unsigned*)(ws + off);
    off += sizeof(unsigned) * (size_t)nbuk * CAP;
    off = (off + 15) & ~(size_t)15;
    _Float16* hpf = (_Float16*)(ws + off);      // layer-1 table, rows>=n zero
    off += (size_t)gb * 64 * DD * 2;
    off = (off + 15) & ~(size_t)15;
    _Float16* hp2 = (_Float16*)(ws + off);      // layer-2 table, rows>=n zero
    off += (size_t)gb * 64 * DD * 2;
    off = (off + 15) & ~(size_t)15;
    _Float16* Wt1 = (_Float16*)(ws + off); off += FIN * DD * 2;
    _Float16* Wt2 = (_Float16*)(ws + off); off += DD * DD * 2;

    int ab = (n + 63) / 64;

    k_prep<<<1, 256, 0, stream>>>(W1, W2, Wt1, Wt2);
    k_histA<<<nbb, 256, 0, stream>>>(dst, hist2d, E, nbuk);
    k_scan2<<<1, 512, 0, stream>>>(hist2d, gcur, nbb);
    k_bucket<<<nbb, 256, 0, stream>>>(src, dst, buf, hist2d, E, nbuk);
    k_csr<<<nbuk, 256, 0, stream>>>(buf, gcur, rowptr, lenp, rs, es, n, n);

    k_gemm1<<<gb, 256, 0, stream>>>(x, Wt1, rs, hpf, n);
    k_aggemm<<<gb, 256, 0, stream>>>((const uint4*)hpf, es, rowptr, lenp, rs,
                                     b1, p1, Wt2, hp2, n);
    k_agg2<<<ab, 256, 0, stream>>>((const uint4*)hp2, es, rowptr, lenp, rs,
                                   b2, p2, out, n);
}

// Round 21
// 153.388 us; speedup vs baseline: 1.1460x; 1.1460x over previous
//
#include <hip/hip_runtime.h>

#define DD 64
#define FIN 128
#define BK 256        // nodes per bucket
#define MAXBUK 512    // supports n <= 131072
#define CAP 8192      // records per bucket region (mean ~4092 at E=1.6M)
#define ESCAP 12288   // padded es slots per bucket
#define EPB 4096      // edges per k_bucket block (16 per thread)

typedef _Float16 half8 __attribute__((ext_vector_type(8)));
typedef _Float16 h2 __attribute__((ext_vector_type(2)));
typedef float f32x4 __attribute__((ext_vector_type(4)));

union U4 { uint4 u; h2 h[4]; };

// pass 1: bucket edges by dst>>8. dst values cached in regs across both passes.
__global__ __launch_bounds__(256) void k_bucket(const int* __restrict__ src,
                                                const int* __restrict__ dst,
                                                unsigned* __restrict__ buf,
                                                int* __restrict__ gcur,
                                                int E, int nbuk) {
    __shared__ int hist[MAXBUK];
    __shared__ int base[MAXBUK];
    int e0 = blockIdx.x * EPB;
    int e1 = min(e0 + EPB, E);
    int dreg[16];
#pragma unroll
    for (int i = 0; i < 16; ++i) {
        int e = e0 + threadIdx.x + i * 256;
        dreg[i] = (e < e1) ? dst[e] : -1;
    }
    for (int i = threadIdx.x; i < nbuk; i += 256) hist[i] = 0;
    __syncthreads();
#pragma unroll
    for (int i = 0; i < 16; ++i)
        if (dreg[i] >= 0) atomicAdd(&hist[dreg[i] >> 8], 1);
    __syncthreads();
    for (int i = threadIdx.x; i < nbuk; i += 256) {
        int c = hist[i];
        base[i] = c ? atomicAdd(&gcur[i], c) : 0;
        hist[i] = 0;  // reuse as local cursor
    }
    __syncthreads();
#pragma unroll
    for (int i = 0; i < 16; ++i) {
        int d = dreg[i];
        if (d >= 0) {
            int e = e0 + threadIdx.x + i * 256;
            int b = d >> 8;
            int off = base[b] + atomicAdd(&hist[b], 1);
            if (off < CAP)
                buf[(size_t)b * CAP + off] = ((unsigned)src[e] << 8) | ((unsigned)d & 255u);
        }
    }
}

// pass 2: one workgroup per bucket. Per-node histogram -> padded (x16) scan ->
// es region at fixed b*ESCAP. Pads point at dummy row (index n, zeroed in gemm1).
__global__ __launch_bounds__(256) void k_csr(const unsigned* __restrict__ buf,
                                             const int* __restrict__ gcur,
                                             int* __restrict__ rowptr,
                                             int* __restrict__ lenp,
                                             float* __restrict__ rs,
                                             int* __restrict__ es, int n, int dummy) {
    __shared__ int cnt[BK];
    __shared__ int excl[BK];
    __shared__ int cur[BK];
    __shared__ int wsum[4];
    int b = blockIdx.x;
    int tid = threadIdx.x;
    int lane = tid & 63, wid = tid >> 6;
    cnt[tid] = 0;
    cur[tid] = 0;
    __syncthreads();
    int count = gcur[b];
    const unsigned* rec = buf + (size_t)b * CAP;
    for (int i = tid; i < count; i += 256)
        atomicAdd(&cnt[rec[i] & (BK - 1)], 1);
    __syncthreads();
    int v = cnt[tid];
    int pv = (v + 15) & ~15;  // padded to multiple of 16
    int s = pv;
    for (int off = 1; off < 64; off <<= 1) {
        int t = __shfl_up(s, off, 64);
        if (lane >= off) s += t;
    }
    if (lane == 63) wsum[wid] = s;
    __syncthreads();
    int wo = 0;
    for (int w = 0; w < wid; ++w) wo += wsum[w];
    excl[tid] = s - pv + wo;
    __syncthreads();
    int node = b * BK + tid;
    int base = b * ESCAP;
    if (node < n) {
        rowptr[node] = base + excl[tid];
        lenp[node] = pv;
        rs[node] = rsqrtf((float)(v + 1));  // +1 self-loop
    }
    for (int i = tid; i < count; i += 256) {
        unsigned r = rec[i];
        int local = r & (BK - 1);
        int pos = base + excl[local] + atomicAdd(&cur[local], 1);
        es[pos] = (int)(r >> 8);
    }
    int st = base + excl[tid];
    for (int i = v; i < pv; ++i) es[st + i] = dummy;
}

// transpose + f16-convert weights; also zeroes gcur.
__global__ __launch_bounds__(256) void k_prep(const float* __restrict__ W1,
                                              const float* __restrict__ W2,
                                              _Float16* __restrict__ Wt1,
                                              _Float16* __restrict__ Wt2,
                                              int* __restrict__ gcur) {
    int tid = threadIdx.x;
    gcur[tid] = 0;
    gcur[tid + 256] = 0;
    for (int i = tid; i < FIN * DD; i += 256) {
        int k = i >> 6, c = i & 63;
        Wt1[c * FIN + k] = (_Float16)W1[i];
    }
    for (int i = tid; i < DD * DD; i += 256) {
        int k = i >> 6, c = i & 63;
        Wt2[c * DD + k] = (_Float16)W2[i];
    }
}

// MFMA f16 GEMM: hpf[row][col] = f16((x[row,:] @ W[:,col]) * rs[row])
__global__ __launch_bounds__(256) void k_gemm1(const float* __restrict__ x,
                                               const _Float16* __restrict__ Wt,
                                               const float* __restrict__ rs,
                                               _Float16* __restrict__ hpf, int n) {
    __shared__ _Float16 sx[64 * 136];
    int row0 = blockIdx.x * 64;
    int tid = threadIdx.x;
    for (int i = tid; i < 2048; i += 256) {  // 64 rows * 32 float4
        int r = i >> 5, c = i & 31;
        int row = row0 + r;
        float4 v = make_float4(0.f, 0.f, 0.f, 0.f);
        if (row < n) v = *(const float4*)(x + (size_t)row * FIN + c * 4);
        union { _Float16 h[4]; uint2 u; } t;
        t.h[0] = (_Float16)v.x; t.h[1] = (_Float16)v.y;
        t.h[2] = (_Float16)v.z; t.h[3] = (_Float16)v.w;
        *(uint2*)(sx + r * 136 + c * 4) = t.u;
    }
    __syncthreads();
    int lane = tid & 63, wave = tid >> 6;
    int r15 = lane & 15, g = lane >> 4;
    half8 a[4];
    const _Float16* ap = sx + (wave * 16 + r15) * 136 + g * 8;
#pragma unroll
    for (int kc = 0; kc < 4; ++kc) a[kc] = *(const half8*)(ap + kc * 32);
    half8 bfr[4][4];
    const _Float16* bp = Wt + (size_t)r15 * FIN + g * 8;
#pragma unroll
    for (int ct = 0; ct < 4; ++ct)
#pragma unroll
        for (int kc = 0; kc < 4; ++kc)
            bfr[ct][kc] = *(const half8*)(bp + ct * 16 * FIN + kc * 32);
    f32x4 acc[4] = {{0.f,0.f,0.f,0.f},{0.f,0.f,0.f,0.f},{0.f,0.f,0.f,0.f},{0.f,0.f,0.f,0.f}};
#pragma unroll
    for (int ct = 0; ct < 4; ++ct)
#pragma unroll
        for (int kc = 0; kc < 4; ++kc)
            acc[ct] = __builtin_amdgcn_mfma_f32_16x16x32_f16(a[kc], bfr[ct][kc], acc[ct], 0, 0, 0);
    __syncthreads();
#pragma unroll
    for (int reg = 0; reg < 4; ++reg) {
        int rowl = wave * 16 + g * 4 + reg;
        int row = row0 + rowl;
        float sc = (row < n) ? rs[row] : 0.f;
#pragma unroll
        for (int ct = 0; ct < 4; ++ct)
            sx[rowl * 72 + ct * 16 + r15] = (_Float16)(acc[ct][reg] * sc);
    }
    __syncthreads();
    for (int i = tid; i < 1024; i += 256) {  // 64 rows * 16 uint2
        int r = i >> 4, q = i & 15;
        uint2 v = *(const uint2*)(sx + r * 72 + q * 4);
        *(uint2*)(hpf + (size_t)(row0 + r) * DD + q * 4) = v;
    }
}

// gather core: 16 nodes/wave, 4 lanes/node; lane owns chunks q and q+4 (32B).
#define GATHER_BODY                                                              \
    int e0 = rowptr[nc];                                                         \
    int len = alive ? lenp[nc] : 0;                                              \
    int nbt = len >> 4;                                                          \
    h2 ac[2][2][4] = {};                                                         \
    {                                                                            \
        U4 t0, t1;                                                               \
        t0.u = hp4[(size_t)nc * 8 + q];                                          \
        t1.u = hp4[(size_t)nc * 8 + q + 4];                                      \
        _Pragma("unroll")                                                        \
        for (int k = 0; k < 4; ++k) { ac[0][0][k] += t0.h[k]; ac[1][0][k] += t1.h[k]; } \
    }                                                                            \
    for (int t = 0; t < nbt; ++t) {                                              \
        uint4 eb = *(const uint4*)(es + e0 + t * 16 + q * 4);                    \
        int jj[16];                                                              \
        _Pragma("unroll")                                                        \
        for (int l = 0; l < 4; ++l) {                                            \
            jj[l]      = __shfl((int)eb.x, l, 4);                                \
            jj[4 + l]  = __shfl((int)eb.y, l, 4);                                \
            jj[8 + l]  = __shfl((int)eb.z, l, 4);                                \
            jj[12 + l] = __shfl((int)eb.w, l, 4);                                \
        }                                                                        \
        _Pragma("unroll")                                                        \
        for (int hb = 0; hb < 2; ++hb) {                                         \
            U4 v0[8], v1[8];                                                     \
            _Pragma("unroll")                                                    \
            for (int m = 0; m < 8; ++m) {                                        \
                size_t bb = (size_t)jj[hb * 8 + m] * 8;                          \
                v0[m].u = hp4[bb + q];                                           \
                v1[m].u = hp4[bb + q + 4];                                       \
            }                                                                    \
            _Pragma("unroll")                                                    \
            for (int m = 0; m < 8; ++m) {                                        \
                _Pragma("unroll")                                                \
                for (int k = 0; k < 4; ++k) {                                    \
                    ac[0][m & 1][k] += v0[m].h[k];                               \
                    ac[1][m & 1][k] += v1[m].h[k];                               \
                }                                                                \
            }                                                                    \
        }                                                                        \
    }                                                                            \
    float F0[8], F1[8];                                                          \
    _Pragma("unroll")                                                            \
    for (int k = 0; k < 4; ++k) {                                                \
        F0[2 * k]     = (float)ac[0][0][k].x + (float)ac[0][1][k].x;             \
        F0[2 * k + 1] = (float)ac[0][0][k].y + (float)ac[0][1][k].y;             \
        F1[2 * k]     = (float)ac[1][0][k].x + (float)ac[1][1][k].x;             \
        F1[2 * k + 1] = (float)ac[1][0][k].y + (float)ac[1][1][k].y;             \
    }

// fused agg1 + relu + gemm2: block = 64 consecutive nodes.
__global__ __launch_bounds__(256) void k_aggemm(const uint4* __restrict__ hp4,
                                                const int* __restrict__ es,
                                                const int* __restrict__ rowptr,
                                                const int* __restrict__ lenp,
                                                const float* __restrict__ rs,
                                                const float* __restrict__ b,
                                                const float* __restrict__ pert,
                                                const _Float16* __restrict__ Wt,
                                                _Float16* __restrict__ hpo, int n) {
    __shared__ _Float16 sx[64 * 72];
    int tid = threadIdx.x;
    int lane = tid & 63, wv = tid >> 6;
    int q = lane & 3, g = lane >> 2;
    int row0 = blockIdx.x * 64;
    int rowl = wv * 16 + g;
    int node = row0 + rowl;
    bool alive = node < n;
    int nc = alive ? node : 0;
    GATHER_BODY
    {
        float r = rs[nc];
        size_t op = (size_t)nc * DD + q * 8;
        float4 p0 = *(const float4*)(pert + op);
        float4 p1 = *(const float4*)(pert + op + 4);
        float4 p2 = *(const float4*)(pert + op + 32);
        float4 p3 = *(const float4*)(pert + op + 36);
        float4 b0 = *(const float4*)(b + q * 8);
        float4 b1 = *(const float4*)(b + q * 8 + 4);
        float4 b2 = *(const float4*)(b + q * 8 + 32);
        float4 b3 = *(const float4*)(b + q * 8 + 36);
        union { _Float16 h[8]; uint4 u; } t0, t1;
        float m = alive ? 1.f : 0.f;
        t0.h[0] = (_Float16)(m * fmaxf(fmaf(r, F0[0], b0.x + p0.x), 0.f));
        t0.h[1] = (_Float16)(m * fmaxf(fmaf(r, F0[1], b0.y + p0.y), 0.f));
        t0.h[2] = (_Float16)(m * fmaxf(fmaf(r, F0[2], b0.z + p0.z), 0.f));
        t0.h[3] = (_Float16)(m * fmaxf(fmaf(r, F0[3], b0.w + p0.w), 0.f));
        t0.h[4] = (_Float16)(m * fmaxf(fmaf(r, F0[4], b1.x + p1.x), 0.f));
        t0.h[5] = (_Float16)(m * fmaxf(fmaf(r, F0[5], b1.y + p1.y), 0.f));
        t0.h[6] = (_Float16)(m * fmaxf(fmaf(r, F0[6], b1.z + p1.z), 0.f));
        t0.h[7] = (_Float16)(m * fmaxf(fmaf(r, F0[7], b1.w + p1.w), 0.f));
        t1.h[0] = (_Float16)(m * fmaxf(fmaf(r, F1[0], b2.x + p2.x), 0.f));
        t1.h[1] = (_Float16)(m * fmaxf(fmaf(r, F1[1], b2.y + p2.y), 0.f));
        t1.h[2] = (_Float16)(m * fmaxf(fmaf(r, F1[2], b2.z + p2.z), 0.f));
        t1.h[3] = (_Float16)(m * fmaxf(fmaf(r, F1[3], b2.w + p2.w), 0.f));
        t1.h[4] = (_Float16)(m * fmaxf(fmaf(r, F1[4], b3.x + p3.x), 0.f));
        t1.h[5] = (_Float16)(m * fmaxf(fmaf(r, F1[5], b3.y + p3.y), 0.f));
        t1.h[6] = (_Float16)(m * fmaxf(fmaf(r, F1[6], b3.z + p3.z), 0.f));
        t1.h[7] = (_Float16)(m * fmaxf(fmaf(r, F1[7], b3.w + p3.w), 0.f));
        *(uint4*)(sx + rowl * 72 + q * 8) = t0.u;
        *(uint4*)(sx + rowl * 72 + q * 8 + 32) = t1.u;
    }
    __syncthreads();
    int r15 = lane & 15, gg = lane >> 4;
    half8 a[2];
    const _Float16* ap = sx + (wv * 16 + r15) * 72 + gg * 8;
#pragma unroll
    for (int kc = 0; kc < 2; ++kc) a[kc] = *(const half8*)(ap + kc * 32);
    half8 bfr[4][2];
    const _Float16* bp = Wt + (size_t)r15 * DD + gg * 8;
#pragma unroll
    for (int ct = 0; ct < 4; ++ct)
#pragma unroll
        for (int kc = 0; kc < 2; ++kc)
            bfr[ct][kc] = *(const half8*)(bp + ct * 16 * DD + kc * 32);
    f32x4 acc[4] = {{0.f,0.f,0.f,0.f},{0.f,0.f,0.f,0.f},{0.f,0.f,0.f,0.f},{0.f,0.f,0.f,0.f}};
#pragma unroll
    for (int ct = 0; ct < 4; ++ct)
#pragma unroll
        for (int kc = 0; kc < 2; ++kc)
            acc[ct] = __builtin_amdgcn_mfma_f32_16x16x32_f16(a[kc], bfr[ct][kc], acc[ct], 0, 0, 0);
    __syncthreads();
#pragma unroll
    for (int reg = 0; reg < 4; ++reg) {
        int rl = wv * 16 + gg * 4 + reg;
        int row = row0 + rl;
        float sc = (row < n) ? rs[row] : 0.f;
#pragma unroll
        for (int ct = 0; ct < 4; ++ct)
            sx[rl * 72 + ct * 16 + r15] = (_Float16)(acc[ct][reg] * sc);
    }
    __syncthreads();
    for (int i = tid; i < 1024; i += 256) {
        int r = i >> 4, qq = i & 15;
        uint2 v = *(const uint2*)(sx + r * 72 + qq * 4);
        *(uint2*)(hpo + (size_t)(row0 + r) * DD + qq * 4) = v;
    }
}

// final aggregation: gather layer-2 rows, epilogue, write f32 out.
__global__ __launch_bounds__(256) void k_agg2(const uint4* __restrict__ hp4,
                                              const int* __restrict__ es,
                                              const int* __restrict__ rowptr,
                                              const int* __restrict__ lenp,
                                              const float* __restrict__ rs,
                                              const float* __restrict__ b,
                                              const float* __restrict__ pert,
                                              float* __restrict__ outp, int n) {
    int tid = threadIdx.x;
    int lane = tid & 63, wv = tid >> 6;
    int q = lane & 3, g = lane >> 2;
    int node = blockIdx.x * 64 + wv * 16 + g;
    bool alive = node < n;
    int nc = alive ? node : 0;
    GATHER_BODY
    if (alive) {
        float r = rs[nc];
        size_t op = (size_t)nc * DD + q * 8;
        float4 p0 = *(const float4*)(pert + op);
        float4 p1 = *(const float4*)(pert + op + 4);
        float4 p2 = *(const float4*)(pert + op + 32);
        float4 p3 = *(const float4*)(pert + op + 36);
        float4 b0 = *(const float4*)(b + q * 8);
        float4 b1 = *(const float4*)(b + q * 8 + 4);
        float4 b2 = *(const float4*)(b + q * 8 + 32);
        float4 b3 = *(const float4*)(b + q * 8 + 36);
        float4 r0, r1, r2, r3;
        r0.x = fmaf(r, F0[0], b0.x + p0.x);
        r0.y = fmaf(r, F0[1], b0.y + p0.y);
        r0.z = fmaf(r, F0[2], b0.z + p0.z);
        r0.w = fmaf(r, F0[3], b0.w + p0.w);
        r1.x = fmaf(r, F0[4], b1.x + p1.x);
        r1.y = fmaf(r, F0[5], b1.y + p1.y);
        r1.z = fmaf(r, F0[6], b1.z + p1.z);
        r1.w = fmaf(r, F0[7], b1.w + p1.w);
        r2.x = fmaf(r, F1[0], b2.x + p2.x);
        r2.y = fmaf(r, F1[1], b2.y + p2.y);
        r2.z = fmaf(r, F1[2], b2.z + p2.z);
        r2.w = fmaf(r, F1[3], b2.w + p2.w);
        r3.x = fmaf(r, F1[4], b3.x + p3.x);
        r3.y = fmaf(r, F1[5], b3.y + p3.y);
        r3.z = fmaf(r, F1[6], b3.z + p3.z);
        r3.w = fmaf(r, F1[7], b3.w + p3.w);
        *(float4*)(outp + op) = r0;
        *(float4*)(outp + op + 4) = r1;
        *(float4*)(outp + op + 32) = r2;
        *(float4*)(outp + op + 36) = r3;
    }
}

extern "C" void kernel_launch(void* const* d_in, const int* in_sizes, int n_in,
                              void* d_out, int out_size, void* d_ws, size_t ws_size,
                              hipStream_t stream) {
    const float* x  = (const float*)d_in[0];
    const int*   ei = (const int*)d_in[1];
    const float* W1 = (const float*)d_in[2];
    const float* b1 = (const float*)d_in[3];
    const float* W2 = (const float*)d_in[4];
    const float* b2 = (const float*)d_in[5];
    const float* p1 = (const float*)d_in[6];
    const float* p2 = (const float*)d_in[7];
    float* out = (float*)d_out;

    int n = in_sizes[0] / FIN;
    int E = in_sizes[1] / 2;
    const int* src = ei;
    const int* dst = ei + E;
    int nbuk = (n + BK - 1) / BK;  // 391 for n=100k
    int gb = (n + 64) / 64;        // covers dummy row n

    char* ws = (char*)d_ws;
    size_t off = 0;
    int* gcur   = (int*)(ws + off); off += sizeof(int) * MAXBUK;
    int* rowptr = (int*)(ws + off); off += sizeof(int) * (size_t)n;
    int* lenp   = (int*)(ws + off); off += sizeof(int) * (size_t)n;
    float* rs   = (float*)(ws + off); off += sizeof(float) * (size_t)n;
    int* es     = (int*)(ws + off); off += sizeof(int) * (size_t)nbuk * ESCAP;
    off = (off + 15) & ~(size_t)15;
    unsigned* buf = (unsigned*)(ws + off);
    off += sizeof(unsigned) * (size_t)nbuk * CAP;
    off = (off + 15) & ~(size_t)15;
    _Float16* hpf = (_Float16*)(ws + off);      // layer-1 table, rows>=n zero
    off += (size_t)gb * 64 * DD * 2;
    off = (off + 15) & ~(size_t)15;
    _Float16* hp2 = (_Float16*)(ws + off);      // layer-2 table, rows>=n zero
    off += (size_t)gb * 64 * DD * 2;
    off = (off + 15) & ~(size_t)15;
    _Float16* Wt1 = (_Float16*)(ws + off); off += FIN * DD * 2;
    _Float16* Wt2 = (_Float16*)(ws + off); off += DD * DD * 2;

    int bb = (E + EPB - 1) / EPB;
    int ab = (n + 63) / 64;

    k_prep<<<1, 256, 0, stream>>>(W1, W2, Wt1, Wt2, gcur);
    k_bucket<<<bb, 256, 0, stream>>>(src, dst, buf, gcur, E, nbuk);
    k_csr<<<nbuk, 256, 0, stream>>>(buf, gcur, rowptr, lenp, rs, es, n, n);

    k_gemm1<<<gb, 256, 0, stream>>>(x, Wt1, rs, hpf, n);
    k_aggemm<<<gb, 256, 0, stream>>>((const uint4*)hpf, es, rowptr, lenp, rs,
                                     b1, p1, Wt2, hp2, n);
    k_agg2<<<ab, 256, 0, stream>>>((const uint4*)hp2, es, rowptr, lenp, rs,
                                   b2, p2, out, n);
}